// Round 2
// baseline (2208.431 us; speedup 1.0000x reference)
//
#include <hip/hip_runtime.h>

typedef __bf16 bf16;
typedef __bf16 bf16x8 __attribute__((ext_vector_type(8)));
typedef float  f32x4  __attribute__((ext_vector_type(4)));

#define BM 128
#define BN 128
#define BKT 64
#define LDK (BKT + 8)

// AMODE: 0 = gather concat [obj[s] | pred | obj[o]] (f32 -> bf16)
//        1 = bn_lrelu(scale*x+shift) applied to bf16 source
//        2 = pooled f32 * invcnt[row]
// EPI:   0 = store bf16 + column stats atomics
//        1 = column stats atomics only (no store)
//        2 = bn_lrelu(out-col scale/shift) then scatter: cols<512 -> pooled[s],
//            512..639 -> outF (new_p), >=640 -> pooled[o]
//        3 = store f32 + column stats atomics
template<int AMODE, int EPI>
__global__ __launch_bounds__(256) void gemm_k(
    const bf16* __restrict__ Abf, const float* __restrict__ Af32,
    const float* __restrict__ obj, const float* __restrict__ pred,
    const int* __restrict__ edges, const float* __restrict__ invcnt,
    const float* __restrict__ scale, const float* __restrict__ shift,   // input-col bn (AMODE==1)
    const float* __restrict__ oscale, const float* __restrict__ oshift, // output-col bn (EPI==2)
    const bf16* __restrict__ WT,      // (N,K) bf16, pre-transposed
    bf16* __restrict__ outB, float* __restrict__ outF,
    float* __restrict__ pooled, float* __restrict__ gsum, float* __restrict__ gsq,
    int M, int N, int K)
{
  __shared__ __align__(16) bf16 As[BM][LDK];
  __shared__ __align__(16) bf16 Bs[BN][LDK];
  __shared__ float sc_sh[512];
  __shared__ float sh_sh[512];
  __shared__ float osc[BN];
  __shared__ float osh[BN];
  __shared__ int eS[BM];
  __shared__ int eO[BM];

  const int tid = threadIdx.x;
  const int m0 = blockIdx.x * BM;
  const int n0 = blockIdx.y * BN;
  const int lane = tid & 63;
  const int w = tid >> 6;
  const int wm = (w >> 1) * 64;
  const int wn = (w & 1) * 64;
  const int l15 = lane & 15;
  const int quad = lane >> 4;

  if (AMODE == 1) {
    for (int c = tid; c < K; c += 256) { sc_sh[c] = scale[c]; sh_sh[c] = shift[c]; }
  }
  if (EPI == 2) {
    if (tid < BN) { osc[tid] = oscale[n0 + tid]; osh[tid] = oshift[n0 + tid]; }
  }
  if (AMODE == 0 || EPI == 2) {
    if (tid < BM) {
      int r = m0 + tid; if (r >= M) r = M - 1;
      eS[tid] = edges[2 * r];
      eO[tid] = edges[2 * r + 1];
    }
  }
  __syncthreads();

  f32x4 acc[4][4];
  #pragma unroll
  for (int i = 0; i < 4; ++i)
    #pragma unroll
    for (int j = 0; j < 4; ++j)
      acc[i][j] = (f32x4){0.f, 0.f, 0.f, 0.f};

  for (int k0 = 0; k0 < K; k0 += BKT) {
    // ---- stage B^T tile: 128 rows (cols of W) x 64 k
    {
      int idx = tid;
      #pragma unroll
      for (int it = 0; it < 4; ++it, idx += 256) {
        int r = idx >> 3, c8 = (idx & 7) << 3;
        bf16x8 v = *reinterpret_cast<const bf16x8*>(WT + (size_t)(n0 + r) * K + k0 + c8);
        *reinterpret_cast<bf16x8*>(&Bs[r][c8]) = v;
      }
    }
    // ---- stage A tile
    if (AMODE == 1) {
      int idx = tid;
      #pragma unroll
      for (int it = 0; it < 4; ++it, idx += 256) {
        int r = idx >> 3, c8 = (idx & 7) << 3;
        int row = m0 + r; if (row >= M) row = M - 1;
        bf16x8 v = *reinterpret_cast<const bf16x8*>(Abf + (size_t)row * K + k0 + c8);
        bf16x8 o;
        #pragma unroll
        for (int e = 0; e < 8; ++e) {
          int c = k0 + c8 + e;
          float f = sc_sh[c] * (float)v[e] + sh_sh[c];
          f = f >= 0.f ? f : 0.2f * f;
          o[e] = (bf16)f;
        }
        *reinterpret_cast<bf16x8*>(&As[r][c8]) = o;
      }
    } else {
      int idx = tid;
      #pragma unroll
      for (int it = 0; it < 8; ++it, idx += 256) {
        int r = idx >> 4, c4 = (idx & 15) << 2;
        int row = m0 + r; if (row >= M) row = M - 1;
        const float* src;
        float mul = 1.f;
        if (AMODE == 0) {
          int k = k0 + c4;
          if (k < 128)      src = obj  + (size_t)eS[r] * 128 + k;
          else if (k < 256) src = pred + (size_t)row * 128 + (k - 128);
          else              src = obj  + (size_t)eO[r] * 128 + (k - 256);
        } else {
          src = Af32 + (size_t)row * K + k0 + c4;
          mul = invcnt[row];
        }
        float4 v = *reinterpret_cast<const float4*>(src);
        As[r][c4 + 0] = (bf16)(v.x * mul);
        As[r][c4 + 1] = (bf16)(v.y * mul);
        As[r][c4 + 2] = (bf16)(v.z * mul);
        As[r][c4 + 3] = (bf16)(v.w * mul);
      }
    }
    __syncthreads();
    #pragma unroll
    for (int kk = 0; kk < BKT; kk += 32) {
      bf16x8 af[4], bfv[4];
      #pragma unroll
      for (int i = 0; i < 4; ++i)
        af[i] = *reinterpret_cast<const bf16x8*>(&As[wm + i * 16 + l15][kk + quad * 8]);
      #pragma unroll
      for (int j = 0; j < 4; ++j)
        bfv[j] = *reinterpret_cast<const bf16x8*>(&Bs[wn + j * 16 + l15][kk + quad * 8]);
      #pragma unroll
      for (int i = 0; i < 4; ++i)
        #pragma unroll
        for (int j = 0; j < 4; ++j)
          acc[i][j] = __builtin_amdgcn_mfma_f32_16x16x32_bf16(af[i], bfv[j], acc[i][j], 0, 0, 0);
    }
    __syncthreads();
  }

  if (EPI == 2) {
    #pragma unroll
    for (int i = 0; i < 4; ++i) {
      #pragma unroll
      for (int r = 0; r < 4; ++r) {
        int lrow = wm + i * 16 + quad * 4 + r;
        int row = m0 + lrow;
        if (row >= M) continue;
        #pragma unroll
        for (int j = 0; j < 4; ++j) {
          int cl = wn + j * 16 + l15;
          int n1 = n0 + cl;
          float v = osc[cl] * acc[i][j][r] + osh[cl];
          v = v >= 0.f ? v : 0.2f * v;
          if (n1 < 512)      atomicAdd(&pooled[(size_t)eS[lrow] * 512 + n1], v);
          else if (n1 < 640) outF[(size_t)row * 128 + (n1 - 512)] = v;
          else               atomicAdd(&pooled[(size_t)eO[lrow] * 512 + (n1 - 640)], v);
        }
      }
    }
  } else {
    #pragma unroll
    for (int j = 0; j < 4; ++j) {
      float s = 0.f, q = 0.f;
      #pragma unroll
      for (int i = 0; i < 4; ++i) {
        #pragma unroll
        for (int r = 0; r < 4; ++r) {
          int row = m0 + wm + i * 16 + quad * 4 + r;
          if (row >= M) continue;
          float v = acc[i][j][r];
          s += v; q += v * v;
          int col = n0 + wn + j * 16 + l15;
          if (EPI == 0) outB[(size_t)row * N + col] = (bf16)v;
          if (EPI == 3) outF[(size_t)row * N + col] = v;
        }
      }
      s += __shfl_xor(s, 16); q += __shfl_xor(q, 16);
      s += __shfl_xor(s, 32); q += __shfl_xor(q, 32);
      if (quad == 0) {
        int col = n0 + wn + j * 16 + l15;
        atomicAdd(&gsum[col], s);
        atomicAdd(&gsq[col], q);
      }
    }
  }
}

// transpose + fp32->bf16 convert: W (K,N) -> WT (N,K)
__global__ __launch_bounds__(256) void tconv_k(const float* __restrict__ W,
                                               bf16* __restrict__ WT, int K, int N) {
  int idx = blockIdx.x * 256 + threadIdx.x;
  if (idx < K * N) {
    int n = idx / K, k = idx - n * K;
    WT[(size_t)n * K + k] = (bf16)W[(size_t)k * N + n];
  }
}

__global__ __launch_bounds__(256) void bnfin_k(const float* __restrict__ sum,
    const float* __restrict__ sq, const float* __restrict__ g,
    const float* __restrict__ be, float* __restrict__ scale,
    float* __restrict__ shift, int C, float invR) {
  int c = blockIdx.x * 256 + threadIdx.x;
  if (c < C) {
    float m = sum[c] * invR;
    float v = sq[c] * invR - m * m;
    float a = g[c] * rsqrtf(v + 1e-5f);
    scale[c] = a;
    shift[c] = be[c] - m * a;
  }
}

__global__ __launch_bounds__(256) void counts_k(const int* __restrict__ edges,
                                                float* __restrict__ counts, int T) {
  int t = blockIdx.x * 256 + threadIdx.x;
  if (t < T) {
    atomicAdd(&counts[edges[2 * t]], 1.f);
    atomicAdd(&counts[edges[2 * t + 1]], 1.f);
  }
}

__global__ __launch_bounds__(256) void invcnt_k(float* __restrict__ counts, int O) {
  int i = blockIdx.x * 256 + threadIdx.x;
  if (i < O) {
    float c = counts[i];
    c = fminf(fmaxf(c, 1.f), (float)O);
    counts[i] = 1.f / c;
  }
}

__global__ __launch_bounds__(256) void final_k(float* __restrict__ buf,
    const float* __restrict__ scale, const float* __restrict__ shift, int n) {
  int i = blockIdx.x * 256 + threadIdx.x;
  if (i < n) {
    int c = i & 127;
    float v = scale[c] * buf[i] + shift[c];
    buf[i] = v >= 0.f ? v : 0.2f * v;
  }
}

extern "C" void kernel_launch(void* const* d_in, const int* in_sizes, int n_in,
                              void* d_out, int out_size, void* d_ws, size_t ws_size,
                              hipStream_t stream) {
  const float* obj   = (const float*)d_in[0];
  const float* pred  = (const float*)d_in[1];
  const int*   edges = (const int*)d_in[2];
  const float* W1a = (const float*)d_in[3];
  const float* g1a = (const float*)d_in[5];
  const float* be1a= (const float*)d_in[6];
  const float* W1b = (const float*)d_in[7];
  const float* g1b = (const float*)d_in[9];
  const float* be1b= (const float*)d_in[10];
  const float* W2a = (const float*)d_in[11];
  const float* g2a = (const float*)d_in[13];
  const float* be2a= (const float*)d_in[14];
  const float* W2b = (const float*)d_in[15];
  const float* g2b = (const float*)d_in[17];
  const float* be2b= (const float*)d_in[18];

  const int O = in_sizes[0] / 128;
  const int T = in_sizes[1] / 128;
  float* out_obj = (float*)d_out;
  float* out_p   = (float*)d_out + (size_t)O * 128;

  char* base = (char*)d_ws;
  size_t off = 0;
  auto alloc = [&](size_t bytes) { size_t p = off; off += (bytes + 255) & ~(size_t)255; return p; };
  size_t oWT1a = alloc((size_t)384 * 512 * 2);
  size_t oWT1b = alloc((size_t)512 * 1152 * 2);
  size_t oWT2a = alloc((size_t)512 * 512 * 2);
  size_t oWT2b = alloc((size_t)512 * 128 * 2);
  size_t oSums = alloc(4608 * 4);
  size_t oScl  = alloc(4608 * 4);
  size_t oCnt  = alloc((size_t)O * 4);
  size_t oHA   = alloc((size_t)T * 512 * 2);   // hA bf16; aliased by h2 after GEMM2
  size_t oPool = alloc((size_t)O * 512 * 4);   // pooled f32

  bf16* WT1a = (bf16*)(base + oWT1a);
  bf16* WT1b = (bf16*)(base + oWT1b);
  bf16* WT2a = (bf16*)(base + oWT2a);
  bf16* WT2b = (bf16*)(base + oWT2b);
  float* sums = (float*)(base + oSums);
  float* sumA = sums,        * sqA = sums + 512;
  float* sumB = sums + 1024, * sqB = sums + 2176;
  float* sumC = sums + 3328, * sqC = sums + 3840;
  float* sumD = sums + 4352, * sqD = sums + 4480;
  float* scl = (float*)(base + oScl);
  float* scaleA = scl,        * shiftA = scl + 512;
  float* scaleB = scl + 1024, * shiftB = scl + 2176;
  float* scaleC = scl + 3328, * shiftC = scl + 3840;
  float* scaleD = scl + 4352, * shiftD = scl + 4480;
  float* counts = (float*)(base + oCnt);
  bf16*  hA = (bf16*)(base + oHA);
  bf16*  h2 = (bf16*)(base + oHA);             // alias: hA dead after GEMM2 pass B
  float* pooled = (float*)(base + oPool);
  float* objpre = out_obj;                     // pre-activations in-place in d_out

  hipMemsetAsync(sums, 0, 4608 * 4, stream);
  hipMemsetAsync(counts, 0, (size_t)O * 4, stream);
  hipMemsetAsync(pooled, 0, (size_t)O * 512 * 4, stream);

  tconv_k<<<(384 * 512 + 255) / 256, 256, 0, stream>>>(W1a, WT1a, 384, 512);
  tconv_k<<<(512 * 1152 + 255) / 256, 256, 0, stream>>>(W1b, WT1b, 512, 1152);
  tconv_k<<<(512 * 512 + 255) / 256, 256, 0, stream>>>(W2a, WT2a, 512, 512);
  tconv_k<<<(512 * 128 + 255) / 256, 256, 0, stream>>>(W2b, WT2b, 512, 128);
  counts_k<<<(T + 255) / 256, 256, 0, stream>>>(edges, counts, T);
  invcnt_k<<<(O + 255) / 256, 256, 0, stream>>>(counts, O);

  // GEMM1: gathered (T,384) @ W1a -> hA bf16 + statsA
  {
    dim3 g((T + BM - 1) / BM, 512 / BN);
    gemm_k<0, 0><<<g, 256, 0, stream>>>(nullptr, nullptr, obj, pred, edges, nullptr,
        nullptr, nullptr, nullptr, nullptr, WT1a, hA, nullptr, nullptr, sumA, sqA,
        T, 512, 384);
  }
  bnfin_k<<<2, 256, 0, stream>>>(sumA, sqA, g1a, be1a, scaleA, shiftA, 512, 1.f / T);

  // GEMM2 pass A: bn_lrelu(hA) (T,512) @ W1b -> statsB only (no store)
  {
    dim3 g((T + BM - 1) / BM, 1152 / BN);
    gemm_k<1, 1><<<g, 256, 0, stream>>>(hA, nullptr, nullptr, nullptr, nullptr, nullptr,
        scaleA, shiftA, nullptr, nullptr, WT1b, nullptr, nullptr, nullptr, sumB, sqB,
        T, 1152, 512);
  }
  bnfin_k<<<5, 256, 0, stream>>>(sumB, sqB, g1b, be1b, scaleB, shiftB, 1152, 1.f / T);

  // GEMM2 pass B: recompute, bn_lrelu, scatter -> out_p + pooled atomics
  {
    dim3 g((T + BM - 1) / BM, 1152 / BN);
    gemm_k<1, 2><<<g, 256, 0, stream>>>(hA, nullptr, nullptr, nullptr, edges, nullptr,
        scaleA, shiftA, scaleB, shiftB, WT1b, nullptr, out_p, pooled, nullptr, nullptr,
        T, 1152, 512);
  }

  // GEMM3: (pooled * invcnt) (O,512) @ W2a -> h2 bf16 + statsC
  {
    dim3 g((O + BM - 1) / BM, 512 / BN);
    gemm_k<2, 0><<<g, 256, 0, stream>>>(nullptr, pooled, nullptr, nullptr, nullptr, counts,
        nullptr, nullptr, nullptr, nullptr, WT2a, h2, nullptr, nullptr, sumC, sqC,
        O, 512, 512);
  }
  bnfin_k<<<2, 256, 0, stream>>>(sumC, sqC, g2a, be2a, scaleC, shiftC, 512, 1.f / O);

  // GEMM4: bn_lrelu(h2) (O,512) @ W2b -> objpre f32 (in d_out) + statsD
  {
    dim3 g((O + BM - 1) / BM, 128 / BN);
    gemm_k<1, 3><<<g, 256, 0, stream>>>(h2, nullptr, nullptr, nullptr, nullptr, nullptr,
        scaleC, shiftC, nullptr, nullptr, WT2b, nullptr, objpre, nullptr, sumD, sqD,
        O, 128, 512);
  }
  bnfin_k<<<1, 256, 0, stream>>>(sumD, sqD, g2b, be2b, scaleD, shiftD, 128, 1.f / O);

  final_k<<<((size_t)O * 128 + 255) / 256, 256, 0, stream>>>(objpre, scaleD, shiftD,
      (int)((size_t)O * 128));
}

// Round 3
// 2150.951 us; speedup vs baseline: 1.0267x; 1.0267x over previous
//
#include <hip/hip_runtime.h>

typedef __bf16 bf16;
typedef __bf16 bf16x8 __attribute__((ext_vector_type(8)));
typedef float  f32x4  __attribute__((ext_vector_type(4)));

#define BM 128
#define BN 128
#define BKT 64
#define LDK (BKT + 8)

// AMODE: 0 = gather concat [obj[s] | pred | obj[o]] (f32 -> bf16)
//        1 = bn_lrelu(scale*x+shift) applied to bf16 source
//        2 = f32 source * invcnt[row]
//        3 = plain bf16 copy
// EPI:   0 = store bf16 + column stats atomics
//        1 = column stats atomics only (no store)
//        2 = bn_lrelu(out-col scale/shift) then scatter: cols<512 -> pooled[s] (atomic),
//            512..639 -> outF (new_p), >=640 -> pooled[o] (atomic)
//        3 = store f32 + column stats atomics
template<int AMODE, int EPI>
__global__ __launch_bounds__(256) void gemm_k(
    const bf16* __restrict__ Abf, const float* __restrict__ Af32,
    const float* __restrict__ obj, const float* __restrict__ pred,
    const int* __restrict__ edges, const float* __restrict__ invcnt,
    const float* __restrict__ scale, const float* __restrict__ shift,   // input-col bn (AMODE==1)
    const float* __restrict__ oscale, const float* __restrict__ oshift, // output-col bn (EPI==2)
    const bf16* __restrict__ WT,      // (N,K) bf16, pre-transposed
    bf16* __restrict__ outB, float* __restrict__ outF,
    float* __restrict__ pooled, float* __restrict__ gsum, float* __restrict__ gsq,
    int M, int N, int K)
{
  __shared__ __align__(16) bf16 As[BM][LDK];
  __shared__ __align__(16) bf16 Bs[BN][LDK];
  __shared__ float sc_sh[(AMODE == 1) ? 512 : 1];
  __shared__ float sh_sh[(AMODE == 1) ? 512 : 1];
  __shared__ float osc[(EPI == 2) ? BN : 1];
  __shared__ float osh[(EPI == 2) ? BN : 1];
  __shared__ int eS[(AMODE == 0 || EPI == 2) ? BM : 1];
  __shared__ int eO[(AMODE == 0 || EPI == 2) ? BM : 1];

  const int tid = threadIdx.x;
  const int m0 = blockIdx.x * BM;
  const int n0 = blockIdx.y * BN;
  const int lane = tid & 63;
  const int w = tid >> 6;
  const int wm = (w >> 1) * 64;
  const int wn = (w & 1) * 64;
  const int l15 = lane & 15;
  const int quad = lane >> 4;

  if (AMODE == 1) {
    for (int c = tid; c < K; c += 256) { sc_sh[c] = scale[c]; sh_sh[c] = shift[c]; }
  }
  if (EPI == 2) {
    if (tid < BN) { osc[tid] = oscale[n0 + tid]; osh[tid] = oshift[n0 + tid]; }
  }
  if (AMODE == 0 || EPI == 2) {
    if (tid < BM) {
      int r = m0 + tid; if (r >= M) r = M - 1;
      eS[tid] = edges[2 * r];
      eO[tid] = edges[2 * r + 1];
    }
  }
  __syncthreads();

  f32x4 acc[4][4];
  #pragma unroll
  for (int i = 0; i < 4; ++i)
    #pragma unroll
    for (int j = 0; j < 4; ++j)
      acc[i][j] = (f32x4){0.f, 0.f, 0.f, 0.f};

  for (int k0 = 0; k0 < K; k0 += BKT) {
    // ---- stage B^T tile: 128 rows (cols of W) x 64 k
    {
      int idx = tid;
      #pragma unroll
      for (int it = 0; it < 4; ++it, idx += 256) {
        int r = idx >> 3, c8 = (idx & 7) << 3;
        bf16x8 v = *reinterpret_cast<const bf16x8*>(WT + (size_t)(n0 + r) * K + k0 + c8);
        *reinterpret_cast<bf16x8*>(&Bs[r][c8]) = v;
      }
    }
    // ---- stage A tile
    if (AMODE == 1 || AMODE == 3) {
      int idx = tid;
      #pragma unroll
      for (int it = 0; it < 4; ++it, idx += 256) {
        int r = idx >> 3, c8 = (idx & 7) << 3;
        int row = m0 + r; if (row >= M) row = M - 1;
        bf16x8 v = *reinterpret_cast<const bf16x8*>(Abf + (size_t)row * K + k0 + c8);
        if (AMODE == 1) {
          bf16x8 o;
          #pragma unroll
          for (int e = 0; e < 8; ++e) {
            int c = k0 + c8 + e;
            float f = sc_sh[c] * (float)v[e] + sh_sh[c];
            f = f >= 0.f ? f : 0.2f * f;
            o[e] = (bf16)f;
          }
          *reinterpret_cast<bf16x8*>(&As[r][c8]) = o;
        } else {
          *reinterpret_cast<bf16x8*>(&As[r][c8]) = v;
        }
      }
    } else {
      int idx = tid;
      #pragma unroll
      for (int it = 0; it < 8; ++it, idx += 256) {
        int r = idx >> 4, c4 = (idx & 15) << 2;
        int row = m0 + r; if (row >= M) row = M - 1;
        const float* src;
        float mul = 1.f;
        if (AMODE == 0) {
          int k = k0 + c4;
          if (k < 128)      src = obj  + (size_t)eS[r] * 128 + k;
          else if (k < 256) src = pred + (size_t)row * 128 + (k - 128);
          else              src = obj  + (size_t)eO[r] * 128 + (k - 256);
        } else {
          src = Af32 + (size_t)row * K + k0 + c4;
          mul = invcnt[row];
        }
        float4 v = *reinterpret_cast<const float4*>(src);
        As[r][c4 + 0] = (bf16)(v.x * mul);
        As[r][c4 + 1] = (bf16)(v.y * mul);
        As[r][c4 + 2] = (bf16)(v.z * mul);
        As[r][c4 + 3] = (bf16)(v.w * mul);
      }
    }
    __syncthreads();
    #pragma unroll
    for (int kk = 0; kk < BKT; kk += 32) {
      bf16x8 af[4], bfv[4];
      #pragma unroll
      for (int i = 0; i < 4; ++i)
        af[i] = *reinterpret_cast<const bf16x8*>(&As[wm + i * 16 + l15][kk + quad * 8]);
      #pragma unroll
      for (int j = 0; j < 4; ++j)
        bfv[j] = *reinterpret_cast<const bf16x8*>(&Bs[wn + j * 16 + l15][kk + quad * 8]);
      #pragma unroll
      for (int i = 0; i < 4; ++i)
        #pragma unroll
        for (int j = 0; j < 4; ++j)
          acc[i][j] = __builtin_amdgcn_mfma_f32_16x16x32_bf16(af[i], bfv[j], acc[i][j], 0, 0, 0);
    }
    __syncthreads();
  }

  if (EPI == 2) {
    #pragma unroll
    for (int i = 0; i < 4; ++i) {
      #pragma unroll
      for (int r = 0; r < 4; ++r) {
        int lrow = wm + i * 16 + quad * 4 + r;
        int row = m0 + lrow;
        if (row >= M) continue;
        #pragma unroll
        for (int j = 0; j < 4; ++j) {
          int cl = wn + j * 16 + l15;
          int n1 = n0 + cl;
          float v = osc[cl] * acc[i][j][r] + osh[cl];
          v = v >= 0.f ? v : 0.2f * v;
          if (n1 < 512)      atomicAdd(&pooled[(size_t)eS[lrow] * 512 + n1], v);
          else if (n1 < 640) outF[(size_t)row * 128 + (n1 - 512)] = v;
          else               atomicAdd(&pooled[(size_t)eO[lrow] * 512 + (n1 - 640)], v);
        }
      }
    }
  } else {
    #pragma unroll
    for (int j = 0; j < 4; ++j) {
      float s = 0.f, q = 0.f;
      #pragma unroll
      for (int i = 0; i < 4; ++i) {
        #pragma unroll
        for (int r = 0; r < 4; ++r) {
          int row = m0 + wm + i * 16 + quad * 4 + r;
          if (row >= M) continue;
          float v = acc[i][j][r];
          s += v; q += v * v;
          int col = n0 + wn + j * 16 + l15;
          if (EPI == 0) outB[(size_t)row * N + col] = (bf16)v;
          if (EPI == 3) outF[(size_t)row * N + col] = v;
        }
      }
      s += __shfl_xor(s, 16); q += __shfl_xor(q, 16);
      s += __shfl_xor(s, 32); q += __shfl_xor(q, 32);
      if (quad == 0) {
        int col = n0 + wn + j * 16 + l15;
        atomicAdd(&gsum[col], s);
        atomicAdd(&gsq[col], q);
      }
    }
  }
}

// transpose + fp32->bf16 convert: W (K,N) -> WT (N,K)
__global__ __launch_bounds__(256) void tconv_k(const float* __restrict__ W,
                                               bf16* __restrict__ WT, int K, int N) {
  int idx = blockIdx.x * 256 + threadIdx.x;
  if (idx < K * N) {
    int n = idx / K, k = idx - n * K;
    WT[(size_t)n * K + k] = (bf16)W[(size_t)k * N + n];
  }
}

__global__ __launch_bounds__(256) void bnfin_k(const float* __restrict__ sum,
    const float* __restrict__ sq, const float* __restrict__ g,
    const float* __restrict__ be, float* __restrict__ scale,
    float* __restrict__ shift, int C, float invR) {
  int c = blockIdx.x * 256 + threadIdx.x;
  if (c < C) {
    float m = sum[c] * invR;
    float v = sq[c] * invR - m * m;
    float a = g[c] * rsqrtf(v + 1e-5f);
    scale[c] = a;
    shift[c] = be[c] - m * a;
  }
}

__global__ __launch_bounds__(256) void cntint_k(const int* __restrict__ edges,
                                                int* __restrict__ cnt, int T) {
  int t = blockIdx.x * 256 + threadIdx.x;
  if (t < T) {
    atomicAdd(&cnt[edges[2 * t]], 1);
    atomicAdd(&cnt[edges[2 * t + 1]], 1);
  }
}

__global__ __launch_bounds__(256) void invcnt_k(const int* __restrict__ cnt,
                                                float* __restrict__ invc, int O) {
  int i = blockIdx.x * 256 + threadIdx.x;
  if (i < O) {
    float c = fminf(fmaxf((float)cnt[i], 1.f), (float)O);
    invc[i] = 1.f / c;
  }
}

// single-block exclusive scan of cnt -> rowptr, head
__global__ __launch_bounds__(1024) void scan_k(const int* __restrict__ cnt,
    int* __restrict__ rowptr, int* __restrict__ head, int O, int total) {
  __shared__ int sh[1024];
  const int t = threadIdx.x;
  const int C = (O + 1023) / 1024;
  const int i0 = t * C;
  int s = 0;
  for (int i = 0; i < C; ++i) { int idx = i0 + i; if (idx < O) s += cnt[idx]; }
  sh[t] = s;
  __syncthreads();
  for (int d = 1; d < 1024; d <<= 1) {
    int v = (t >= d) ? sh[t - d] : 0;
    __syncthreads();
    sh[t] += v;
    __syncthreads();
  }
  int run = (t == 0) ? 0 : sh[t - 1];
  for (int i = 0; i < C; ++i) {
    int idx = i0 + i;
    if (idx < O) { rowptr[idx] = run; head[idx] = run; run += cnt[idx]; }
  }
  if (t == 0) rowptr[O] = total;
}

__global__ __launch_bounds__(256) void fill_k(const int* __restrict__ edges,
    int* __restrict__ head, int* __restrict__ list, int T) {
  int t = blockIdx.x * 256 + threadIdx.x;
  if (t < T) {
    int s = edges[2 * t];
    int p = atomicAdd(&head[s], 1);
    list[p] = t << 1;
    int o = edges[2 * t + 1];
    p = atomicAdd(&head[o], 1);
    list[p] = (t << 1) | 1;
  }
}

// in-place A2 = bn_lrelu(hA)
__global__ __launch_bounds__(256) void act_k(bf16* __restrict__ hA,
    const float* __restrict__ scale, const float* __restrict__ shift, size_t n8) {
  size_t i = (size_t)blockIdx.x * 256 + threadIdx.x;
  if (i < n8) {
    size_t idx8 = i * 8;
    int c = (int)(idx8 & 511);
    bf16x8 v = *reinterpret_cast<const bf16x8*>(hA + idx8);
    bf16x8 o;
    #pragma unroll
    for (int j = 0; j < 8; ++j) {
      float f = scale[c + j] * (float)v[j] + shift[c + j];
      f = f >= 0.f ? f : 0.2f * f;
      o[j] = (bf16)f;
    }
    *reinterpret_cast<bf16x8*>(hA + idx8) = o;
  }
}

// new_p = bn_lrelu(tB[:,512:640]) -> out_p f32
__global__ __launch_bounds__(256) void newp_k(const bf16* __restrict__ tB,
    const float* __restrict__ scale, const float* __restrict__ shift,
    float* __restrict__ outP, int T) {
  int i = blockIdx.x * 256 + threadIdx.x;
  if (i < T * 128) {
    int t = i >> 7, c = i & 127;
    float v = scale[512 + c] * (float)tB[(size_t)t * 1152 + 512 + c] + shift[512 + c];
    outP[i] = v >= 0.f ? v : 0.2f * v;
  }
}

// one wave per object: pooled[o] = invc[o] * sum over incident edges of
// bn_lrelu(tB[t, role-cols])   (role s -> cols 0..511, role o -> cols 640..1151)
__global__ __launch_bounds__(256) void gather_k(const bf16* __restrict__ tB,
    const int* __restrict__ rowptr, const int* __restrict__ list,
    const float* __restrict__ scale, const float* __restrict__ shift,
    const float* __restrict__ invc, bf16* __restrict__ pooled, int O) {
  int o = blockIdx.x * 4 + (threadIdx.x >> 6);
  if (o >= O) return;
  int lane = threadIdx.x & 63;
  int c0 = lane * 8;
  float scS[8], shS[8], scO[8], shO[8];
  #pragma unroll
  for (int j = 0; j < 8; ++j) {
    scS[j] = scale[c0 + j];       shS[j] = shift[c0 + j];
    scO[j] = scale[640 + c0 + j]; shO[j] = shift[640 + c0 + j];
  }
  float acc[8];
  #pragma unroll
  for (int j = 0; j < 8; ++j) acc[j] = 0.f;
  int e0 = rowptr[o], e1 = rowptr[o + 1];
  for (int e = e0; e < e1; ++e) {
    int id = list[e];
    int t = id >> 1;
    int role = id & 1;
    const bf16* row = tB + (size_t)t * 1152 + (role ? 640 : 0) + c0;
    bf16x8 v = *reinterpret_cast<const bf16x8*>(row);
    if (role) {
      #pragma unroll
      for (int j = 0; j < 8; ++j) {
        float f = scO[j] * (float)v[j] + shO[j];
        acc[j] += (f >= 0.f ? f : 0.2f * f);
      }
    } else {
      #pragma unroll
      for (int j = 0; j < 8; ++j) {
        float f = scS[j] * (float)v[j] + shS[j];
        acc[j] += (f >= 0.f ? f : 0.2f * f);
      }
    }
  }
  float ic = invc[o];
  bf16x8 out;
  #pragma unroll
  for (int j = 0; j < 8; ++j) out[j] = (bf16)(acc[j] * ic);
  *reinterpret_cast<bf16x8*>(pooled + (size_t)o * 512 + c0) = out;
}

__global__ __launch_bounds__(256) void final_k(float* __restrict__ buf,
    const float* __restrict__ scale, const float* __restrict__ shift, int n) {
  int i = blockIdx.x * 256 + threadIdx.x;
  if (i < n) {
    int c = i & 127;
    float v = scale[c] * buf[i] + shift[c];
    buf[i] = v >= 0.f ? v : 0.2f * v;
  }
}

extern "C" void kernel_launch(void* const* d_in, const int* in_sizes, int n_in,
                              void* d_out, int out_size, void* d_ws, size_t ws_size,
                              hipStream_t stream) {
  const float* obj   = (const float*)d_in[0];
  const float* pred  = (const float*)d_in[1];
  const int*   edges = (const int*)d_in[2];
  const float* W1a = (const float*)d_in[3];
  const float* g1a = (const float*)d_in[5];
  const float* be1a= (const float*)d_in[6];
  const float* W1b = (const float*)d_in[7];
  const float* g1b = (const float*)d_in[9];
  const float* be1b= (const float*)d_in[10];
  const float* W2a = (const float*)d_in[11];
  const float* g2a = (const float*)d_in[13];
  const float* be2a= (const float*)d_in[14];
  const float* W2b = (const float*)d_in[15];
  const float* g2b = (const float*)d_in[17];
  const float* be2b= (const float*)d_in[18];

  const int O = in_sizes[0] / 128;
  const int T = in_sizes[1] / 128;
  float* out_obj = (float*)d_out;
  float* out_p   = (float*)d_out + (size_t)O * 128;

  // ---- workspace layout (staged path needs tB; fallback reuses its slot for f32 pooled)
  char* base = (char*)d_ws;
  size_t off = 0;
  auto alloc = [&](size_t bytes) { size_t p = off; off += (bytes + 255) & ~(size_t)255; return p; };
  size_t oWT1a = alloc((size_t)384 * 512 * 2);
  size_t oWT1b = alloc((size_t)512 * 1152 * 2);
  size_t oWT2a = alloc((size_t)512 * 512 * 2);
  size_t oWT2b = alloc((size_t)512 * 128 * 2);
  size_t oSums = alloc(4608 * 4);
  size_t oScl  = alloc(4608 * 4);
  size_t oCntI = alloc((size_t)O * 4);
  size_t oInvc = alloc((size_t)O * 4);
  size_t oRp   = alloc((size_t)(O + 1) * 4);
  size_t oHead = alloc((size_t)O * 4);
  size_t oList = alloc((size_t)2 * T * 4);
  size_t oHA   = alloc((size_t)T * 512 * 2);    // hA/A2 bf16; h2 aliases later
  size_t oBig  = off;                           // staged: tB bf16 T*1152 then pooled bf16
                                                // fallback: pooled f32 O*512
  size_t need_staged = oBig + (((size_t)T * 1152 * 2 + 255) & ~(size_t)255)
                            + (size_t)O * 512 * 2;
  size_t need_fb     = oBig + (size_t)O * 512 * 4;
  const bool staged = (ws_size >= need_staged);

  bf16* WT1a = (bf16*)(base + oWT1a);
  bf16* WT1b = (bf16*)(base + oWT1b);
  bf16* WT2a = (bf16*)(base + oWT2a);
  bf16* WT2b = (bf16*)(base + oWT2b);
  float* sums = (float*)(base + oSums);
  float* sumA = sums,        * sqA = sums + 512;
  float* sumB = sums + 1024, * sqB = sums + 2176;
  float* sumC = sums + 3328, * sqC = sums + 3840;
  float* sumD = sums + 4352, * sqD = sums + 4480;
  float* scl = (float*)(base + oScl);
  float* scaleA = scl,        * shiftA = scl + 512;
  float* scaleB = scl + 1024, * shiftB = scl + 2176;
  float* scaleC = scl + 3328, * shiftC = scl + 3840;
  float* scaleD = scl + 4352, * shiftD = scl + 4480;
  int*   cntI = (int*)(base + oCntI);
  float* invc = (float*)(base + oInvc);
  int*   rowptr = (int*)(base + oRp);
  int*   head = (int*)(base + oHead);
  int*   list = (int*)(base + oList);
  bf16*  hA = (bf16*)(base + oHA);     // also A2 (in-place), later h2
  bf16*  h2 = (bf16*)(base + oHA);
  bf16*  tB = (bf16*)(base + oBig);
  bf16*  pooledB = (bf16*)(base + oBig + (((size_t)T * 1152 * 2 + 255) & ~(size_t)255));
  float* pooledF = (float*)(base + oBig);
  float* objpre = out_obj;

  hipMemsetAsync(sums, 0, 4608 * 4, stream);
  hipMemsetAsync(cntI, 0, (size_t)O * 4, stream);

  tconv_k<<<(384 * 512 + 255) / 256, 256, 0, stream>>>(W1a, WT1a, 384, 512);
  tconv_k<<<(512 * 1152 + 255) / 256, 256, 0, stream>>>(W1b, WT1b, 512, 1152);
  tconv_k<<<(512 * 512 + 255) / 256, 256, 0, stream>>>(W2a, WT2a, 512, 512);
  tconv_k<<<(512 * 128 + 255) / 256, 256, 0, stream>>>(W2b, WT2b, 512, 128);
  cntint_k<<<(T + 255) / 256, 256, 0, stream>>>(edges, cntI, T);
  invcnt_k<<<(O + 255) / 256, 256, 0, stream>>>(cntI, invc, O);
  if (staged) {
    scan_k<<<1, 1024, 0, stream>>>(cntI, rowptr, head, O, 2 * T);
    fill_k<<<(T + 255) / 256, 256, 0, stream>>>(edges, head, list, T);
  }

  // GEMM1: gathered (T,384) @ W1a -> hA raw bf16 + statsA
  {
    dim3 g((T + BM - 1) / BM, 512 / BN);
    gemm_k<0, 0><<<g, 256, 0, stream>>>(nullptr, nullptr, obj, pred, edges, nullptr,
        nullptr, nullptr, nullptr, nullptr, WT1a, hA, nullptr, nullptr, sumA, sqA,
        T, 512, 384);
  }
  bnfin_k<<<2, 256, 0, stream>>>(sumA, sqA, g1a, be1a, scaleA, shiftA, 512, 1.f / T);

  // A2 = bn_lrelu(hA) in-place
  act_k<<<(int)(((size_t)T * 512 / 8 + 255) / 256), 256, 0, stream>>>(hA, scaleA, shiftA,
      (size_t)T * 512 / 8);

  if (staged) {
    // GEMM2 (single pass): A2 (T,512) @ W1b -> raw tB bf16 + statsB
    {
      dim3 g((T + BM - 1) / BM, 1152 / BN);
      gemm_k<3, 0><<<g, 256, 0, stream>>>(hA, nullptr, nullptr, nullptr, nullptr, nullptr,
          nullptr, nullptr, nullptr, nullptr, WT1b, tB, nullptr, nullptr, sumB, sqB,
          T, 1152, 512);
    }
    bnfin_k<<<5, 256, 0, stream>>>(sumB, sqB, g1b, be1b, scaleB, shiftB, 1152, 1.f / T);

    newp_k<<<(T * 128 + 255) / 256, 256, 0, stream>>>(tB, scaleB, shiftB, out_p, T);
    gather_k<<<(O + 3) / 4, 256, 0, stream>>>(tB, rowptr, list, scaleB, shiftB, invc,
        pooledB, O);

    // GEMM3: pooled bf16 (O,512) @ W2a -> h2 bf16 + statsC
    {
      dim3 g((O + BM - 1) / BM, 512 / BN);
      gemm_k<3, 0><<<g, 256, 0, stream>>>(pooledB, nullptr, nullptr, nullptr, nullptr,
          nullptr, nullptr, nullptr, nullptr, nullptr, WT2a, h2, nullptr, nullptr,
          sumC, sqC, O, 512, 512);
    }
  } else {
    // fallback: two-pass GEMM2 with atomic scatter into f32 pooled
    hipMemsetAsync(pooledF, 0, (size_t)O * 512 * 4, stream);
    {
      dim3 g((T + BM - 1) / BM, 1152 / BN);
      gemm_k<3, 1><<<g, 256, 0, stream>>>(hA, nullptr, nullptr, nullptr, nullptr, nullptr,
          nullptr, nullptr, nullptr, nullptr, WT1b, nullptr, nullptr, nullptr, sumB, sqB,
          T, 1152, 512);
    }
    bnfin_k<<<5, 256, 0, stream>>>(sumB, sqB, g1b, be1b, scaleB, shiftB, 1152, 1.f / T);
    {
      dim3 g((T + BM - 1) / BM, 1152 / BN);
      gemm_k<3, 2><<<g, 256, 0, stream>>>(hA, nullptr, nullptr, nullptr, edges, nullptr,
          nullptr, nullptr, scaleB, shiftB, WT1b, nullptr, out_p, pooledF, nullptr,
          nullptr, T, 1152, 512);
    }
    // GEMM3: (pooledF * invc) (O,512) @ W2a -> h2 bf16 + statsC
    {
      dim3 g((O + BM - 1) / BM, 512 / BN);
      gemm_k<2, 0><<<g, 256, 0, stream>>>(nullptr, pooledF, nullptr, nullptr, nullptr,
          invc, nullptr, nullptr, nullptr, nullptr, WT2a, h2, nullptr, nullptr,
          sumC, sqC, O, 512, 512);
    }
  }
  bnfin_k<<<2, 256, 0, stream>>>(sumC, sqC, g2a, be2a, scaleC, shiftC, 512, 1.f / O);

  // GEMM4: bn_lrelu(h2) (O,512) @ W2b -> objpre f32 (in d_out) + statsD
  {
    dim3 g((O + BM - 1) / BM, 128 / BN);
    gemm_k<1, 3><<<g, 256, 0, stream>>>(h2, nullptr, nullptr, nullptr, nullptr, nullptr,
        scaleC, shiftC, nullptr, nullptr, WT2b, nullptr, objpre, nullptr, sumD, sqD,
        O, 128, 512);
  }
  bnfin_k<<<1, 256, 0, stream>>>(sumD, sqD, g2b, be2b, scaleD, shiftD, 128, 1.f / O);

  final_k<<<((size_t)O * 128 + 255) / 256, 256, 0, stream>>>(objpre, scaleD, shiftD,
      (int)((size_t)O * 128));
}